// Round 1
// baseline (250.013 us; speedup 1.0000x reference)
//
#include <hip/hip_runtime.h>
#include <stdint.h>

#define DD 512
#define HH 8
#define DOO 64
#define ALPHA 0.2f

typedef __attribute__((ext_vector_type(8))) short short8;
typedef __attribute__((ext_vector_type(4))) float floatx4;
typedef __attribute__((ext_vector_type(4))) unsigned short u16x4;
typedef unsigned short u16;

static __device__ __forceinline__ float bf2f(u16 u){
  union { unsigned int u; float f; } c; c.u = ((unsigned int)u) << 16; return c.f;
}
static __device__ __forceinline__ u16 f2bf(float f){
  union { float f; unsigned int u; } c; c.f = f;
  unsigned int u = c.u;
  unsigned int r = (u + 0x7FFFu + ((u >> 16) & 1u)) >> 16;
  return (u16)r;
}
static __device__ __forceinline__ float leaky(float s){ return (s >= 0.f) ? s : ALPHA * s; }
static __device__ __forceinline__ float elu(float v){ return (v > 0.f) ? v : (__expf(v) - 1.f); }

// (z0c, z1c) bf16 pair from two edges' dwords: lo16 = z0's bf16, hi16 = z1's bf16
// v_perm pool: sel 0-3 -> src1 bytes, 4-7 -> src0 bytes
#define PERM_LO 0x01000504u
#define PERM_HI 0x03020706u

#define DOT2(accv, pairv, wv) \
  asm("v_dot2_f32_bf16 %0, %1, %2, %0" : "+v"(accv) : "v"(pairv), "v"(wv))

#define DOTS8(ZA, ZB, AQ) do{ unsigned pr_; \
  pr_=__builtin_amdgcn_perm((ZA).x,(ZB).x,PERM_LO); DOT2(acc[0],pr_,(AQ)); \
  pr_=__builtin_amdgcn_perm((ZA).x,(ZB).x,PERM_HI); DOT2(acc[1],pr_,(AQ)); \
  pr_=__builtin_amdgcn_perm((ZA).y,(ZB).y,PERM_LO); DOT2(acc[2],pr_,(AQ)); \
  pr_=__builtin_amdgcn_perm((ZA).y,(ZB).y,PERM_HI); DOT2(acc[3],pr_,(AQ)); \
  pr_=__builtin_amdgcn_perm((ZA).z,(ZB).z,PERM_LO); DOT2(acc[4],pr_,(AQ)); \
  pr_=__builtin_amdgcn_perm((ZA).z,(ZB).z,PERM_HI); DOT2(acc[5],pr_,(AQ)); \
  pr_=__builtin_amdgcn_perm((ZA).w,(ZB).w,PERM_LO); DOT2(acc[6],pr_,(AQ)); \
  pr_=__builtin_amdgcn_perm((ZA).w,(ZB).w,PERM_HI); DOT2(acc[7],pr_,(AQ)); \
}while(0)

#define GLOAD_LDS16(g, l) \
  __builtin_amdgcn_global_load_lds((const __attribute__((address_space(1))) void*)(g), \
                                   (__attribute__((address_space(3))) void*)(l), 16, 0, 0)

// ---------------- fused prep: x->bf16, W1 transpose, Wout transpose, degree count ----------------
__global__ void k_prep(const float* __restrict__ h, u16* __restrict__ xb,
                       const float* __restrict__ W1, u16* __restrict__ wbt1,
                       const float* __restrict__ Wout, u16* __restrict__ wbt2,
                       const int* __restrict__ dst, int* deg,
                       int n4, int E){
  int i = blockIdx.x * blockDim.x + threadIdx.x;
  if (i < n4){
    float4 v = ((const float4*)h)[i];
    u16x4 o;
    o[0] = f2bf(v.x); o[1] = f2bf(v.y); o[2] = f2bf(v.z); o[3] = f2bf(v.w);
    ((u16x4*)xb)[i] = o;
    return;
  }
  i -= n4;
  if (i < HH * DD * DOO / 8){
    int idx0 = i * 8;
    #pragma unroll
    for (int t = 0; t < 8; t++){
      int idx = idx0 + t;
      int hh = idx >> 15;
      int rem = idx & 32767;
      int k = rem >> 6;
      int dd = rem & 63;
      wbt1[(hh * 64 + dd) * DD + k] = f2bf(W1[idx]);
    }
    return;
  }
  i -= HH * DD * DOO / 8;
  if (i < DD * DD){
    int k = i >> 9, n = i & 511;
    wbt2[n * DD + k] = f2bf(Wout[i]);
    return;
  }
  i -= DD * DD;
  if (i < E) atomicAdd(&deg[dst[i]], 1);
}

// ---------------- CSR build (degrees padded to EVEN so edge-pairs are aligned) ----------------
__global__ void k_scan(const int* __restrict__ deg, int* __restrict__ off, int N){
  __shared__ int sm[1024];
  int tid = threadIdx.x;
  const int per = 16;
  int base = tid * per;
  int loc[per];
  int t = 0;
  #pragma unroll
  for (int i = 0; i < per; i++){
    int v = (base + i < N) ? deg[base + i] : 0;
    v = (v + 1) & ~1;                       // pad each node's edge list to even count
    loc[i] = v; t += v;
  }
  sm[tid] = t; __syncthreads();
  for (int o = 1; o < 1024; o <<= 1){
    int v = 0;
    if (tid >= o) v = sm[tid - o];
    __syncthreads();
    sm[tid] += v;
    __syncthreads();
  }
  int run = sm[tid] - t;
  #pragma unroll
  for (int i = 0; i < per; i++){ if (base + i < N) off[base + i] = run; run += loc[i]; }
  if (tid == 1023) off[N] = run;
}

__global__ void k_scatter(const int* __restrict__ src, const int* __restrict__ dst,
                          const int* __restrict__ off, int* cursor, int* __restrict__ csr, int E){
  int i = blockIdx.x * blockDim.x + threadIdx.x;
  if (i < E){
    int d = dst[i];
    int p = atomicAdd(&cursor[d], 1);
    csr[off[d] + p] = src[i];
  }
}

// ---------------- bf16 MFMA GEMM: BK=64, XOR-swizzled LDS, n-fastest grid ----------------
__global__ __launch_bounds__(256) void k_gemm(const u16* __restrict__ A,
                                              const u16* __restrict__ BT,
                                              u16* __restrict__ C, int M){
  __shared__ __attribute__((aligned(16))) u16 As[128 * 64];
  __shared__ __attribute__((aligned(16))) u16 Bs[128 * 64];
  const int tid = threadIdx.x;
  const int wid = tid >> 6, lane = tid & 63;
  const int n0 = blockIdx.x * 128, m0 = blockIdx.y * 128;
  const int wr = wid >> 1, wc = wid & 1;
  const int row16 = lane & 15, kg = lane >> 4;
  floatx4 acc[4][4];
  #pragma unroll
  for (int i = 0; i < 4; i++)
    #pragma unroll
    for (int j = 0; j < 4; j++) acc[i][j] = (floatx4)0.0f;

  for (int kt = 0; kt < DD; kt += 64){
    #pragma unroll
    for (int i = 0; i < 4; i++){
      int chunk = i * 256 + tid;          // LDS granule 0..1023 (linear dest)
      int m = chunk >> 3, g = chunk & 7;
      int gs = g ^ (m & 7);               // inverse-swizzled global source granule
      GLOAD_LDS16(A + (size_t)(m0 + m) * DD + kt + gs * 8, &As[chunk * 8]);
      GLOAD_LDS16(BT + (size_t)(n0 + m) * DD + kt + gs * 8, &Bs[chunk * 8]);
    }
    __syncthreads();
    short8 af[4][2], bf[4][2];
    #pragma unroll
    for (int mi = 0; mi < 4; mi++)
      #pragma unroll
      for (int kk = 0; kk < 2; kk++){
        int row = wr * 64 + mi * 16 + row16;
        int gr = (kk * 4 + kg) ^ (row & 7);
        af[mi][kk] = *(const short8*)(&As[(row * 8 + gr) * 8]);
      }
    #pragma unroll
    for (int ni = 0; ni < 4; ni++)
      #pragma unroll
      for (int kk = 0; kk < 2; kk++){
        int row = wc * 64 + ni * 16 + row16;
        int gr = (kk * 4 + kg) ^ (row & 7);
        bf[ni][kk] = *(const short8*)(&Bs[(row * 8 + gr) * 8]);
      }
    #pragma unroll
    for (int kk = 0; kk < 2; kk++)
      #pragma unroll
      for (int mi = 0; mi < 4; mi++)
        #pragma unroll
        for (int ni = 0; ni < 4; ni++)
          acc[mi][ni] = __builtin_amdgcn_mfma_f32_16x16x32_bf16(af[mi][kk], bf[ni][kk], acc[mi][ni], 0, 0, 0);
    __syncthreads();
  }
  #pragma unroll
  for (int mi = 0; mi < 4; mi++)
    #pragma unroll
    for (int ni = 0; ni < 4; ni++)
      #pragma unroll
      for (int j = 0; j < 4; j++){
        int r = m0 + wr * 64 + mi * 16 + kg * 4 + j;
        int c = n0 + wc * 64 + ni * 16 + row16;
        C[(size_t)r * DD + c] = f2bf(acc[mi][ni][j]);
      }
}

// ---------------- attention scores ----------------
__global__ void k_scores1(const u16* __restrict__ z, const float* __restrict__ a1,
                          float* __restrict__ es, float* __restrict__ ed, int N){
  int wid = threadIdx.x >> 6, lane = threadIdx.x & 63;
  int n = blockIdx.x * 4 + wid;
  if (n >= N) return;
  int h = lane >> 3, j8 = lane & 7;
  short8 zv = *(const short8*)(z + (size_t)n * DD + lane * 8);
  float esv = 0.f, edv = 0.f;
  #pragma unroll
  for (int t = 0; t < 8; t++){
    float f = bf2f((u16)zv[t]);
    esv += f * a1[h * 128 + j8 * 8 + t];
    edv += f * a1[h * 128 + 64 + j8 * 8 + t];
  }
  #pragma unroll
  for (int d2 = 1; d2 < 8; d2 <<= 1){ esv += __shfl_xor(esv, d2); edv += __shfl_xor(edv, d2); }
  if (j8 == 0){ es[n * 8 + h] = esv; ed[n * 8 + h] = edv; }
}

__global__ void k_scores2(const u16* __restrict__ z, const float* __restrict__ aout,
                          float* __restrict__ es, float* __restrict__ ed, int N){
  int wid = threadIdx.x >> 6, lane = threadIdx.x & 63;
  int n = blockIdx.x * 4 + wid;
  if (n >= N) return;
  short8 zv = *(const short8*)(z + (size_t)n * DD + lane * 8);
  float esv = 0.f, edv = 0.f;
  #pragma unroll
  for (int t = 0; t < 8; t++){
    float f = bf2f((u16)zv[t]);
    esv += f * aout[lane * 8 + t];
    edv += f * aout[512 + lane * 8 + t];
  }
  #pragma unroll
  for (int d2 = 1; d2 < 64; d2 <<= 1){ esv += __shfl_xor(esv, d2); edv += __shfl_xor(edv, d2); }
  if (lane == 0){ es[n] = esv; ed[n] = edv; }
}

// ---------------- edge weights, hoisted out of aggregation ----------------
// One wave per node. For each edge: w = exp(leaky(es[src]+ed[n])) per head (unnormalized,
// same numerics as before); pack consecutive CSR pairs as bf16x2 (dot2 operand format);
// wave-reduce den[n][h] in f32; fill pad slot (odd degree) with src=0 / w=0.
__global__ void k_edgew1(const float* __restrict__ es, const float* __restrict__ ed,
                         const int* __restrict__ off, const int* __restrict__ deg,
                         int* __restrict__ csr, unsigned* __restrict__ wp,
                         float* __restrict__ den1, int N, int ep2){
  int wid = threadIdx.x >> 6, lane = threadIdx.x & 63;
  int n = blockIdx.x * 4 + wid;
  if (n >= N) return;
  int o0 = off[n], cntp = off[n + 1] - o0, cnt = deg[n];
  float edh[8];
  {
    float4 d0 = *(const float4*)(ed + (size_t)n * 8);
    float4 d1 = *(const float4*)(ed + (size_t)n * 8 + 4);
    edh[0]=d0.x; edh[1]=d0.y; edh[2]=d0.z; edh[3]=d0.w;
    edh[4]=d1.x; edh[5]=d1.y; edh[6]=d1.z; edh[7]=d1.w;
  }
  float den[8];
  #pragma unroll
  for (int h = 0; h < 8; h++) den[h] = 0.f;
  for (int base = 0; base < cntp; base += 64){
    int e = base + lane;
    float wv[8];
    if (e < cnt){
      int s = csr[o0 + e];
      float4 e0 = *(const float4*)(es + (size_t)s * 8);
      float4 e1 = *(const float4*)(es + (size_t)s * 8 + 4);
      float ev[8] = {e0.x, e0.y, e0.z, e0.w, e1.x, e1.y, e1.z, e1.w};
      #pragma unroll
      for (int h = 0; h < 8; h++){
        float w = __expf(leaky(ev[h] + edh[h]));
        wv[h] = w; den[h] += w;
      }
    } else {
      if (e < cntp) csr[o0 + e] = 0;      // pad slot: valid gather target, zero weight
      #pragma unroll
      for (int h = 0; h < 8; h++) wv[h] = 0.f;
    }
    #pragma unroll
    for (int h = 0; h < 8; h++){
      float wn = __shfl_down(wv[h], 1);
      if (!(lane & 1) && e < cntp){
        unsigned pk;
        asm("v_cvt_pk_bf16_f32 %0, %1, %2" : "=v"(pk) : "v"(wv[h]), "v"(wn));
        wp[(size_t)h * ep2 + ((o0 + e) >> 1)] = pk;
      }
    }
  }
  #pragma unroll
  for (int h = 0; h < 8; h++){
    float d = den[h];
    #pragma unroll
    for (int d2 = 1; d2 < 64; d2 <<= 1) d += __shfl_xor(d, d2);
    if (lane == 0) den1[(size_t)n * 8 + h] = d;
  }
}

__global__ void k_edgew2(const float* __restrict__ es, const float* __restrict__ ed,
                         const int* __restrict__ off, const int* __restrict__ deg,
                         int* __restrict__ csr, unsigned* __restrict__ wp,
                         float* __restrict__ den2, int N){
  int wid = threadIdx.x >> 6, lane = threadIdx.x & 63;
  int n = blockIdx.x * 4 + wid;
  if (n >= N) return;
  int o0 = off[n], cntp = off[n + 1] - o0, cnt = deg[n];
  float edn = ed[n];
  float dsum = 0.f;
  for (int base = 0; base < cntp; base += 64){
    int e = base + lane;
    float w = 0.f;
    if (e < cnt){
      int s = csr[o0 + e];
      w = __expf(leaky(es[s] + edn));
      dsum += w;
    } else if (e < cntp){
      csr[o0 + e] = 0;
    }
    float wn = __shfl_down(w, 1);
    if (!(lane & 1) && e < cntp){
      unsigned pk;
      asm("v_cvt_pk_bf16_f32 %0, %1, %2" : "=v"(pk) : "v"(w), "v"(wn));
      wp[(o0 + e) >> 1] = pk;
    }
  }
  #pragma unroll
  for (int d2 = 1; d2 < 64; d2 <<= 1) dsum += __shfl_xor(dsum, d2);
  if (lane == 0) den2[n] = dsum;
}

// ---------------- column-tiled aggregation: pure pipelined weighted gather ----------------
// grid (N/4, 4); blockIdx.y = pass p over cols [p*128, p*128+128).
// Wave = 4 groups x 16 lanes; each group handles one edge PAIR per stage; lane li covers 8 cols.
// Weights pre-packed bf16x2 per pair, CSR pre-padded to even; no exp / den / shuffles in-loop.
// 2-deep software pipeline (masked loads, zero-filled tails) hides gather latency.
__global__ __launch_bounds__(256) void k_agg1(const u16* __restrict__ z,
    const unsigned* __restrict__ wp, const float* __restrict__ den1,
    const int* __restrict__ off, const int* __restrict__ csr,
    u16* __restrict__ hcat, int N, int ep2){
  int wid = threadIdx.x >> 6, lane = threadIdx.x & 63;
  int n = blockIdx.x * 4 + wid;
  if (n >= N) return;
  int p = blockIdx.y;
  int o0 = off[n];
  int npairs = (off[n + 1] - o0) >> 1;
  int qb = o0 >> 1;
  int g = lane >> 4, li = lane & 15;
  int head = 2 * p + (li >> 3);
  const unsigned* wph = wp + (size_t)head * ep2 + qb;
  const int2* cp = (const int2*)csr + qb;
  int coloff = p * 128 + li * 8;
  const u16* zc = z + coloff;
  float acc[8];
  #pragma unroll
  for (int j = 0; j < 8; j++) acc[j] = 0.f;

  uint4 zA0 = {0,0,0,0}, zA1 = {0,0,0,0}, zB0 = {0,0,0,0}, zB1 = {0,0,0,0};
  unsigned aqA = 0, aqB = 0;
  {
    int q0 = g, q1 = 4 + g;
    if (q0 < npairs){
      int2 sp = cp[q0]; aqA = wph[q0];
      zA0 = *(const uint4*)(zc + (size_t)sp.x * DD);
      zA1 = *(const uint4*)(zc + (size_t)sp.y * DD);
    }
    if (q1 < npairs){
      int2 sp = cp[q1]; aqB = wph[q1];
      zB0 = *(const uint4*)(zc + (size_t)sp.x * DD);
      zB1 = *(const uint4*)(zc + (size_t)sp.y * DD);
    }
  }
  int itn = (npairs + 3) >> 2;
  for (int it = 2; it < itn + 2; it += 2){
    int q2 = it * 4 + g, q3 = q2 + 4;
    bool v2 = q2 < npairs, v3 = q3 < npairs;
    int2 sp2 = {0,0}, sp3 = {0,0};
    unsigned naqA = 0, naqB = 0;
    if (v2){ sp2 = cp[q2]; naqA = wph[q2]; }
    if (v3){ sp3 = cp[q3]; naqB = wph[q3]; }
    DOTS8(zA0, zA1, aqA);
    uint4 nzA0 = {0,0,0,0}, nzA1 = {0,0,0,0};
    if (v2){
      nzA0 = *(const uint4*)(zc + (size_t)sp2.x * DD);
      nzA1 = *(const uint4*)(zc + (size_t)sp2.y * DD);
    }
    DOTS8(zB0, zB1, aqB);
    uint4 nzB0 = {0,0,0,0}, nzB1 = {0,0,0,0};
    if (v3){
      nzB0 = *(const uint4*)(zc + (size_t)sp3.x * DD);
      nzB1 = *(const uint4*)(zc + (size_t)sp3.y * DD);
    }
    zA0 = nzA0; zA1 = nzA1; aqA = naqA;
    zB0 = nzB0; zB1 = nzB1; aqB = naqB;
  }
  #pragma unroll
  for (int j = 0; j < 8; j++){
    acc[j] += __shfl_xor(acc[j], 16);
    acc[j] += __shfl_xor(acc[j], 32);
  }
  if (lane < 16){
    float inv = 1.f / den1[(size_t)n * 8 + head];
    short8 o;
    #pragma unroll
    for (int j = 0; j < 8; j++) o[j] = (short)f2bf(elu(acc[j] * inv));
    *(short8*)(hcat + (size_t)n * DD + coloff) = o;
  }
}

__global__ __launch_bounds__(256) void k_agg2(const u16* __restrict__ z,
    const unsigned* __restrict__ wp, const float* __restrict__ den2,
    const int* __restrict__ off, const int* __restrict__ csr,
    const u16* __restrict__ xb, float* __restrict__ out, int N){
  int wid = threadIdx.x >> 6, lane = threadIdx.x & 63;
  int n = blockIdx.x * 4 + wid;
  if (n >= N) return;
  int p = blockIdx.y;
  int o0 = off[n];
  int npairs = (off[n + 1] - o0) >> 1;
  int qb = o0 >> 1;
  int g = lane >> 4, li = lane & 15;
  const unsigned* wph = wp + qb;
  const int2* cp = (const int2*)csr + qb;
  int coloff = p * 128 + li * 8;
  const u16* zc = z + coloff;
  float acc[8];
  #pragma unroll
  for (int j = 0; j < 8; j++) acc[j] = 0.f;

  uint4 zA0 = {0,0,0,0}, zA1 = {0,0,0,0}, zB0 = {0,0,0,0}, zB1 = {0,0,0,0};
  unsigned aqA = 0, aqB = 0;
  {
    int q0 = g, q1 = 4 + g;
    if (q0 < npairs){
      int2 sp = cp[q0]; aqA = wph[q0];
      zA0 = *(const uint4*)(zc + (size_t)sp.x * DD);
      zA1 = *(const uint4*)(zc + (size_t)sp.y * DD);
    }
    if (q1 < npairs){
      int2 sp = cp[q1]; aqB = wph[q1];
      zB0 = *(const uint4*)(zc + (size_t)sp.x * DD);
      zB1 = *(const uint4*)(zc + (size_t)sp.y * DD);
    }
  }
  int itn = (npairs + 3) >> 2;
  for (int it = 2; it < itn + 2; it += 2){
    int q2 = it * 4 + g, q3 = q2 + 4;
    bool v2 = q2 < npairs, v3 = q3 < npairs;
    int2 sp2 = {0,0}, sp3 = {0,0};
    unsigned naqA = 0, naqB = 0;
    if (v2){ sp2 = cp[q2]; naqA = wph[q2]; }
    if (v3){ sp3 = cp[q3]; naqB = wph[q3]; }
    DOTS8(zA0, zA1, aqA);
    uint4 nzA0 = {0,0,0,0}, nzA1 = {0,0,0,0};
    if (v2){
      nzA0 = *(const uint4*)(zc + (size_t)sp2.x * DD);
      nzA1 = *(const uint4*)(zc + (size_t)sp2.y * DD);
    }
    DOTS8(zB0, zB1, aqB);
    uint4 nzB0 = {0,0,0,0}, nzB1 = {0,0,0,0};
    if (v3){
      nzB0 = *(const uint4*)(zc + (size_t)sp3.x * DD);
      nzB1 = *(const uint4*)(zc + (size_t)sp3.y * DD);
    }
    zA0 = nzA0; zA1 = nzA1; aqA = naqA;
    zB0 = nzB0; zB1 = nzB1; aqB = naqB;
  }
  #pragma unroll
  for (int j = 0; j < 8; j++){
    acc[j] += __shfl_xor(acc[j], 16);
    acc[j] += __shfl_xor(acc[j], 32);
  }
  if (lane < 16){
    float inv = 1.f / den2[n];
    short8 xv = *(const short8*)(xb + (size_t)n * DD + coloff);
    float ov[8];
    #pragma unroll
    for (int j = 0; j < 8; j++) ov[j] = elu(acc[j] * inv) + bf2f((u16)xv[j]);
    float4 o0v, o1v;
    o0v.x = ov[0]; o0v.y = ov[1]; o0v.z = ov[2]; o0v.w = ov[3];
    o1v.x = ov[4]; o1v.y = ov[5]; o1v.z = ov[6]; o1v.w = ov[7];
    *(float4*)(out + (size_t)n * DD + coloff) = o0v;
    *(float4*)(out + (size_t)n * DD + coloff + 4) = o1v;
  }
}

// ---------------- launcher ----------------
extern "C" void kernel_launch(void* const* d_in, const int* in_sizes, int n_in,
                              void* d_out, int out_size, void* d_ws, size_t ws_size,
                              hipStream_t stream){
  const float* h   = (const float*)d_in[0];
  const float* W1  = (const float*)d_in[1];
  const float* a1  = (const float*)d_in[2];
  const float* Wout= (const float*)d_in[3];
  const float* aout= (const float*)d_in[4];
  const int* src   = (const int*)d_in[5];
  const int* dst   = (const int*)d_in[6];
  float* out = (float*)d_out;
  const int N = in_sizes[0] / DD;     // 16384
  const int E = in_sizes[5];          // 540672
  const int EP = E + N;               // padded-CSR capacity (<=1 pad slot per node)
  const int ep2 = EP >> 1;            // pair stride per head

  char* p = (char*)d_ws;
  auto alloc = [&](size_t bytes) -> char* {
    char* r = p;
    p += (bytes + 255) & ~(size_t)255;
    return r;
  };
  u16* xb    = (u16*)alloc((size_t)N * DD * 2);
  u16* z1b   = (u16*)alloc((size_t)N * DD * 2);   // reused as z2b
  u16* hcat  = (u16*)alloc((size_t)N * DD * 2);
  u16* wbt1  = (u16*)alloc((size_t)DD * DD * 2);
  u16* wbt2  = (u16*)alloc((size_t)DD * DD * 2);
  float* es1 = (float*)alloc((size_t)N * HH * 4);
  float* ed1 = (float*)alloc((size_t)N * HH * 4);
  float* es2 = (float*)alloc((size_t)N * 4);
  float* ed2 = (float*)alloc((size_t)N * 4);
  float* den1= (float*)alloc((size_t)N * HH * 4);
  float* den2= (float*)alloc((size_t)N * 4);
  int* deg   = (int*)alloc((size_t)N * 4);
  int* off   = (int*)alloc((size_t)(N + 1) * 4);
  int* cursor= (int*)alloc((size_t)N * 4);
  int* csr   = (int*)alloc((size_t)EP * 4);
  unsigned* wp1 = (unsigned*)alloc((size_t)HH * ep2 * 4);
  unsigned* wp2 = (unsigned*)alloc((size_t)ep2 * 4);

  // one memset covers deg..cursor (off is fully rewritten by k_scan)
  hipMemsetAsync(deg, 0, (size_t)((char*)csr - (char*)deg), stream);

  int n4 = N * DD / 4;
  int prep_threads = n4 + HH * DD * DOO / 8 + DD * DD + E;
  k_prep<<<(prep_threads + 255) / 256, 256, 0, stream>>>(h, xb, W1, wbt1, Wout, wbt2, dst, deg, n4, E);
  k_scan<<<1, 1024, 0, stream>>>(deg, off, N);
  k_scatter<<<(E + 255) / 256, 256, 0, stream>>>(src, dst, off, cursor, csr, E);

  dim3 gg(DD / 128, N / 128);     // x = n-tile (4), y = m-tile (128): A-panel reuse
  dim3 ga((N + 3) / 4, 4);
  dim3 gw((N + 3) / 4);

  k_gemm<<<gg, 256, 0, stream>>>(xb, wbt1, z1b, N);
  k_scores1<<<(N + 3) / 4, 256, 0, stream>>>(z1b, a1, es1, ed1, N);
  k_edgew1<<<gw, 256, 0, stream>>>(es1, ed1, off, deg, csr, wp1, den1, N, ep2);
  k_agg1<<<ga, 256, 0, stream>>>(z1b, wp1, den1, off, csr, hcat, N, ep2);

  k_gemm<<<gg, 256, 0, stream>>>(hcat, wbt2, z1b, N);
  k_scores2<<<(N + 3) / 4, 256, 0, stream>>>(z1b, aout, es2, ed2, N);
  k_edgew2<<<gw, 256, 0, stream>>>(es2, ed2, off, deg, csr, wp2, den2, N);
  k_agg2<<<ga, 256, 0, stream>>>(z1b, wp2, den2, off, csr, xb, out, N);
}